// Round 5
// baseline (405.358 us; speedup 1.0000x reference)
//
#include <hip/hip_runtime.h>
#include <hip/hip_bf16.h>

// Problem constants (from reference)
constexpr int N   = 100000;   // nodes
constexpr int E   = 1600000;  // edges
constexpr int G   = 512;      // graphs
constexpr int L   = 1000;     // target seq len
constexpr int NPG = 195;      // N // G  (contiguous batch assignment)

// Padded-slot CSR: 48 slots per node. In-degree ~ Poisson(16); P(deg>48) ~ 3e-12
// per node, so no real edge is ever dropped for this input. The drop branch only
// guarantees memory safety for adversarial inputs.
constexpr int SLOTS  = 48;
constexpr int NRANGE = 8;       // dest ranges, XCD-pinned via blockIdx&7
constexpr int RSPAN  = 12500;   // nodes per range (2.4 MB slot window -> L2-resident)
constexpr int NCHUNK = 256;     // edge chunks per range
constexpr int CHUNK  = (E + NCHUNK - 1) / NCHUNK;  // 6250

__device__ __forceinline__ float bf2f(__hip_bfloat16 b) { return __bfloat162float(b); }

// ---------------- init: slot cursors + pooled-max buffer ----------------

__global__ void k_init(int* __restrict__ cursor, float* __restrict__ gbuf) {
    int i = blockIdx.x * 256 + threadIdx.x;
    if (i < N) cursor[i] = i * SLOTS;
    if (i < G * 128) gbuf[i] = 0.0f;
}

// ---------------- bucket: XCD-range-confined scatter into padded slots ----------------
// blockIdx&7 selects a dest range; blockIdx>>3 an edge chunk. Edge-index streams are
// non-temporal so they do NOT evict the L2-resident slot window (round-4 counters:
// WRITE 78 MB from stream-pollution evictions of partially filled slot lines).

__global__ void __launch_bounds__(256) k_bucket(
        const int* __restrict__ row, const int* __restrict__ col,
        int* __restrict__ cursor, int* __restrict__ slots) {
    int r = blockIdx.x & (NRANGE - 1);
    int c = blockIdx.x >> 3;
    int lo = r * RSPAN, hi = lo + RSPAN;
    int e1 = min((c + 1) * CHUNK, E);
    for (int e = c * CHUNK + threadIdx.x; e < e1; e += 256) {
        int d = __builtin_nontemporal_load(col + e);
        if (d >= lo && d < hi) {
            int p = atomicAdd(&cursor[d], 1);
            int src = __builtin_nontemporal_load(row + e);
            if (p < d * SLOTS + SLOTS) slots[p] = src;
        }
    }
}

// dis = rsqrt(deg), deg = in-degree + 1 (self-loop); in-degree = cursor[n] - 48n
__global__ void k_dis(const int* __restrict__ cursor, float* __restrict__ dis) {
    int i = blockIdx.x * 256 + threadIdx.x;
    if (i < N) dis[i] = rsqrtf((float)(cursor[i] - i * SLOTS + 1));
}

// ---------------- layer 1: gather raw x (4 feats) ----------------

__global__ void __launch_bounds__(256) k_gather_x(
        const int* __restrict__ cursor, const int* __restrict__ slots,
        const float* __restrict__ dis, const float4* __restrict__ x,
        float4* __restrict__ aggx) {
    int n = blockIdx.x * 256 + threadIdx.x;
    if (n >= N) return;
    int s = n * SLOTS;
    int cnt = min(cursor[n] - s, SLOTS);
    float dn = dis[n];
    // accumulate sum_j dis[src_j] * x[src_j]; scale by dn at the end
    float4 a = make_float4(0.f, 0.f, 0.f, 0.f);
    int j = 0;
    for (; j + 4 <= cnt; j += 4) {
        int s0 = __builtin_nontemporal_load(slots + s + j);
        int s1 = __builtin_nontemporal_load(slots + s + j + 1);
        int s2 = __builtin_nontemporal_load(slots + s + j + 2);
        int s3 = __builtin_nontemporal_load(slots + s + j + 3);
        float w0 = dis[s0], w1 = dis[s1], w2 = dis[s2], w3 = dis[s3];
        float4 v0 = x[s0], v1 = x[s1], v2 = x[s2], v3 = x[s3];
        a.x = fmaf(v0.x, w0, a.x); a.y = fmaf(v0.y, w0, a.y);
        a.z = fmaf(v0.z, w0, a.z); a.w = fmaf(v0.w, w0, a.w);
        a.x = fmaf(v1.x, w1, a.x); a.y = fmaf(v1.y, w1, a.y);
        a.z = fmaf(v1.z, w1, a.z); a.w = fmaf(v1.w, w1, a.w);
        a.x = fmaf(v2.x, w2, a.x); a.y = fmaf(v2.y, w2, a.y);
        a.z = fmaf(v2.z, w2, a.z); a.w = fmaf(v2.w, w2, a.w);
        a.x = fmaf(v3.x, w3, a.x); a.y = fmaf(v3.y, w3, a.y);
        a.z = fmaf(v3.z, w3, a.z); a.w = fmaf(v3.w, w3, a.w);
    }
    for (; j < cnt; j++) {
        int sx = __builtin_nontemporal_load(slots + s + j);
        float w = dis[sx];
        float4 v = x[sx];
        a.x = fmaf(v.x, w, a.x); a.y = fmaf(v.y, w, a.y);
        a.z = fmaf(v.z, w, a.z); a.w = fmaf(v.w, w, a.w);
    }
    float4 xs = x[n];
    float sl = dn * dn;            // self-loop weight 1/deg
    a.x = fmaf(xs.x, sl, a.x * dn);
    a.y = fmaf(xs.y, sl, a.y * dn);
    a.z = fmaf(xs.z, sl, a.z * dn);
    a.w = fmaf(xs.w, sl, a.w * dn);
    aggx[n] = a;
}

// h = relu(aggx @ W1 + b1), stored bf16
__global__ void __launch_bounds__(256) k_layer1(
        const float4* __restrict__ aggx,
        const float* __restrict__ W1, const float* __restrict__ b1,
        __hip_bfloat16* __restrict__ h) {
    __shared__ float w1s[256];
    __shared__ float b1s[64];
    int tid = threadIdx.x;
    w1s[tid] = W1[tid];
    if (tid < 64) b1s[tid] = b1[tid];
    __syncthreads();
    int idx = blockIdx.x * 256 + tid;   // n*64 + f
    int n = idx >> 6;
    int f = idx & 63;
    if (n >= N) return;
    float4 a = aggx[n];
    float v = b1s[f];
    v = fmaf(a.x, w1s[f], v);
    v = fmaf(a.y, w1s[64 + f], v);
    v = fmaf(a.z, w1s[128 + f], v);
    v = fmaf(a.w, w1s[192 + f], v);
    h[idx] = __float2bfloat16(fmaxf(v, 0.0f));
}

// ---------------- layer 2 gather: one wave per node, lane = feature; bf16 out ----------------

__global__ void __launch_bounds__(256) k_gather_h(
        const int* __restrict__ cursor, const int* __restrict__ slots,
        const float* __restrict__ dis, const __hip_bfloat16* __restrict__ h,
        __hip_bfloat16* __restrict__ aggh) {
    int tid = threadIdx.x;
    int n = blockIdx.x * 4 + (tid >> 6);
    int lane = tid & 63;
    if (n >= N) return;
    int s = n * SLOTS;
    int cnt = min(cursor[n] - s, SLOTS);
    float dn = dis[n];
    float acc = 0.0f;                  // sum_j dis[src_j] * h[src_j]; scale by dn later
    int j = 0;
    for (; j + 8 <= cnt; j += 8) {
        int sr[8]; float w[8]; float v[8];
        #pragma unroll
        for (int k = 0; k < 8; k++) sr[k] = __builtin_nontemporal_load(slots + s + j + k);
        #pragma unroll
        for (int k = 0; k < 8; k++) w[k] = dis[sr[k]];
        #pragma unroll
        for (int k = 0; k < 8; k++) v[k] = bf2f(h[(size_t)sr[k] * 64 + lane]);
        #pragma unroll
        for (int k = 0; k < 8; k++) acc = fmaf(w[k], v[k], acc);
    }
    for (; j < cnt; j++) {
        int sx = __builtin_nontemporal_load(slots + s + j);
        acc = fmaf(dis[sx], bf2f(h[(size_t)sx * 64 + lane]), acc);
    }
    float self = bf2f(h[(size_t)n * 64 + lane]);
    aggh[(size_t)n * 64 + lane] =
        __float2bfloat16(fmaf(dn, self, acc) * dn);  // dn^2*self + dn*sum
}

// ---------------- fused: h2 = relu(aggh@W2+b2) -> segment_max into g ----------------
// Register-blocked: 4 nodes per wave, 16 per block. Per k: 2 lane-reads + 4
// broadcasts + 8 FMAs (old: 3 LDS + 2 FMA per node => 12 LDS per 4 nodes).
// relu output >= 0, g init = 0  =>  int-bitwise atomicMax == float max.

__global__ void __launch_bounds__(256) k_layer2_pool(
        const __hip_bfloat16* __restrict__ aggh, const float* __restrict__ W2,
        const float* __restrict__ b2, float* __restrict__ g) {
    __shared__ float w2s[64 * 128];
    __shared__ float b2s[128];
    __shared__ float rows[16 * 64];
    int tid = threadIdx.x;
    for (int i = tid; i < 64 * 128; i += 256) w2s[i] = W2[i];
    if (tid < 128) b2s[tid] = b2[tid];
    int wid = tid >> 6, lane = tid & 63;
    __syncthreads();
    for (int base = blockIdx.x * 16; base < N; base += gridDim.x * 16) {
        int nrows = min(16, N - base);
        for (int i = tid; i < nrows * 64; i += 256)
            rows[i] = bf2f(aggh[(size_t)base * 64 + i]);
        __syncthreads();
        float acc[4][2];
        #pragma unroll
        for (int i = 0; i < 4; i++) { acc[i][0] = b2s[lane]; acc[i][1] = b2s[64 + lane]; }
        #pragma unroll 4
        for (int k = 0; k < 64; k++) {
            float w0 = w2s[k * 128 + lane];
            float w1 = w2s[k * 128 + 64 + lane];
            #pragma unroll
            for (int i = 0; i < 4; i++) {
                float r = rows[(wid * 4 + i) * 64 + k];       // LDS broadcast
                acc[i][0] = fmaf(r, w0, acc[i][0]);
                acc[i][1] = fmaf(r, w1, acc[i][1]);
            }
        }
        #pragma unroll
        for (int i = 0; i < 4; i++) {
            int n = base + wid * 4 + i;
            if (n < N) {
                float a0 = fmaxf(acc[i][0], 0.0f);
                float a1 = fmaxf(acc[i][1], 0.0f);
                int gr = n / NPG; if (gr > G - 1) gr = G - 1;
                atomicMax((int*)&g[gr * 128 + lane], __float_as_int(a0));
                atomicMax((int*)&g[gr * 128 + 64 + lane], __float_as_int(a1));
            }
        }
        __syncthreads();   // protect rows before next-iter overwrite
    }
}

// ---------------- conv1d branch: per-graph, LDS-staged, sliding window ----------------

__global__ void __launch_bounds__(256) k_conv(
        const float* __restrict__ target, const float* __restrict__ Wc,
        const float* __restrict__ bc, float* __restrict__ tb) {
    __shared__ float tg[L * 5];     // 20 KB: target[g] as [pos][ci]
    __shared__ float pm[4 * 64];
    int tid = threadIdx.x;
    int gi = blockIdx.x;
    const float* tsrc = target + (size_t)gi * (L * 5);
    for (int i = tid; i < L * 5; i += 256) tg[i] = tsrc[i];
    __syncthreads();
    int co = tid & 63, rr = tid >> 6;
    float wc[15];
    #pragma unroll
    for (int j = 0; j < 15; j++) wc[j] = Wc[co * 15 + j];
    int p0 = rr * 250;
    int pend = min(p0 + 250, 998);
    float a0 = tg[p0 * 5 + 0], a1 = tg[p0 * 5 + 1], a2 = tg[p0 * 5 + 2],
          a3 = tg[p0 * 5 + 3], a4 = tg[p0 * 5 + 4];
    float b0 = tg[p0 * 5 + 5], b1 = tg[p0 * 5 + 6], b2 = tg[p0 * 5 + 7],
          b3 = tg[p0 * 5 + 8], b4 = tg[p0 * 5 + 9];
    float m = -1e30f;
    for (int p = p0; p < pend; p++) {
        const float* cp = &tg[(p + 2) * 5];
        float c0 = cp[0], c1 = cp[1], c2 = cp[2], c3 = cp[3], c4 = cp[4];
        float v = 0.0f;
        v = fmaf(a0, wc[0],  v); v = fmaf(b0, wc[1],  v); v = fmaf(c0, wc[2],  v);
        v = fmaf(a1, wc[3],  v); v = fmaf(b1, wc[4],  v); v = fmaf(c1, wc[5],  v);
        v = fmaf(a2, wc[6],  v); v = fmaf(b2, wc[7],  v); v = fmaf(c2, wc[8],  v);
        v = fmaf(a3, wc[9],  v); v = fmaf(b3, wc[10], v); v = fmaf(c3, wc[11], v);
        v = fmaf(a4, wc[12], v); v = fmaf(b4, wc[13], v); v = fmaf(c4, wc[14], v);
        m = fmaxf(m, v);
        a0 = b0; a1 = b1; a2 = b2; a3 = b3; a4 = b4;
        b0 = c0; b1 = c1; b2 = c2; b3 = c3; b4 = c4;
    }
    pm[rr * 64 + co] = m;
    __syncthreads();
    if (tid < 64) {
        float mm = fmaxf(fmaxf(pm[tid], pm[64 + tid]), fmaxf(pm[128 + tid], pm[192 + tid]));
        tb[gi * 64 + tid] = fmaxf(mm + bc[tid], 0.0f);   // relu(max+bc) == max relu(v+bc)
    }
}

// ---------------- head ----------------

__global__ void __launch_bounds__(64) k_head(
        const float* __restrict__ g, const float* __restrict__ tb,
        const float* __restrict__ Wg, const float* __restrict__ bg,
        const float* __restrict__ Wt, const float* __restrict__ bt,
        const float* __restrict__ Wf, const float* __restrict__ bf,
        const float* __restrict__ Wo, const float* __restrict__ bo,
        float* __restrict__ out) {
    __shared__ float grs[128], ts[64], g2s[64], t2s[64], xcs[64];
    int tid = threadIdx.x;
    int gi = blockIdx.x;
    grs[tid]      = g[gi * 128 + tid];
    grs[64 + tid] = g[gi * 128 + 64 + tid];
    ts[tid]       = tb[gi * 64 + tid];
    __syncthreads();
    float a = bg[tid];
    #pragma unroll 8
    for (int k = 0; k < 128; k++) a = fmaf(grs[k], Wg[k * 64 + tid], a);
    float b = bt[tid];
    #pragma unroll 8
    for (int k = 0; k < 64; k++) b = fmaf(ts[k], Wt[k * 64 + tid], b);
    g2s[tid] = a;
    t2s[tid] = b;
    __syncthreads();
    float c = bf[tid];
    #pragma unroll 8
    for (int k = 0; k < 64; k++) c = fmaf(g2s[k], Wf[k * 64 + tid], c);
    #pragma unroll 8
    for (int k = 0; k < 64; k++) c = fmaf(t2s[k], Wf[(64 + k) * 64 + tid], c);
    c = fmaxf(c, 0.0f);
    xcs[tid] = c;
    __syncthreads();
    if (tid < 2) {
        float o = bo[tid];
        for (int k = 0; k < 64; k++) o = fmaf(xcs[k], Wo[k * 2 + tid], o);
        out[gi * 2 + tid] = o;
    }
}

// ---------------- launch ----------------

extern "C" void kernel_launch(void* const* d_in, const int* in_sizes, int n_in,
                              void* d_out, int out_size, void* d_ws, size_t ws_size,
                              hipStream_t stream) {
    const float* x      = (const float*)d_in[0];
    const int*   ei     = (const int*)d_in[1];   // [2, E] int32
    const float* target = (const float*)d_in[3];
    const float* W1 = (const float*)d_in[4];
    const float* b1 = (const float*)d_in[5];
    const float* W2 = (const float*)d_in[6];
    const float* b2 = (const float*)d_in[7];
    const float* Wg = (const float*)d_in[8];
    const float* bg = (const float*)d_in[9];
    const float* Wc = (const float*)d_in[10];
    const float* bc = (const float*)d_in[11];
    const float* Wt = (const float*)d_in[12];
    const float* bt = (const float*)d_in[13];
    const float* Wf = (const float*)d_in[14];
    const float* bf = (const float*)d_in[15];
    const float* Wo = (const float*)d_in[16];
    const float* bo = (const float*)d_in[17];
    float* out = (float*)d_out;

    const int* row = ei;
    const int* col = ei + E;

    // Workspace carve-up, 256B-aligned blocks
    char* base = (char*)d_ws;
    size_t o = 0;
    auto alloc = [&](size_t bytes) -> void* {
        void* p = base + o;
        o = (o + bytes + 255) & ~(size_t)255;
        return p;
    };
    int*      cursor = (int*)     alloc((size_t)N * 4);
    float*    dis    = (float*)   alloc((size_t)N * 4);
    int*      slots  = (int*)     alloc((size_t)N * SLOTS * 4);  // 19.2 MB
    float*    aggx   = (float*)   alloc((size_t)N * 4 * 4);
    __hip_bfloat16* h    = (__hip_bfloat16*)alloc((size_t)N * 64 * 2);
    __hip_bfloat16* aggh = (__hip_bfloat16*)alloc((size_t)N * 64 * 2);
    float*    gbuf   = (float*)   alloc((size_t)G * 128 * 4);
    float*    tb     = (float*)   alloc((size_t)G * 64 * 4);

    k_init       <<<(N + 255) / 256, 256, 0, stream>>>(cursor, gbuf);
    k_bucket     <<<NRANGE * NCHUNK, 256, 0, stream>>>(row, col, cursor, slots);
    k_dis        <<<(N + 255) / 256, 256, 0, stream>>>(cursor, dis);
    k_gather_x   <<<(N + 255) / 256, 256, 0, stream>>>(cursor, slots, dis,
                                                       (const float4*)x, (float4*)aggx);
    k_layer1     <<<(N * 64 + 255) / 256, 256, 0, stream>>>((const float4*)aggx, W1, b1, h);
    k_gather_h   <<<(N + 3) / 4, 256, 0, stream>>>(cursor, slots, dis, h, aggh);
    k_layer2_pool<<<1024, 256, 0, stream>>>(aggh, W2, b2, gbuf);
    k_conv       <<<G, 256, 0, stream>>>(target, Wc, bc, tb);
    k_head       <<<G, 64, 0, stream>>>(gbuf, tb, Wg, bg, Wt, bt, Wf, bf, Wo, bo, out);
}

// Round 6
// 363.931 us; speedup vs baseline: 1.1138x; 1.1138x over previous
//
#include <hip/hip_runtime.h>
#include <hip/hip_bf16.h>

// Problem constants (from reference)
constexpr int N   = 100000;   // nodes
constexpr int E   = 1600000;  // edges
constexpr int G   = 512;      // graphs
constexpr int L   = 1000;     // target seq len
constexpr int NPG = 195;      // N // G  (contiguous batch assignment)

// Padded-slot CSR: 48 slots per node. In-degree ~ Poisson(16); P(deg>48) ~ 3e-12
// per node, so no real edge is ever dropped for this input. The drop branch only
// guarantees memory safety for adversarial inputs.
constexpr int SLOTS  = 48;
constexpr int NRANGE = 8;       // dest ranges, XCD-pinned via blockIdx&7
constexpr int RSPAN  = 12500;   // nodes per range (2.4 MB slot window -> L2-resident)
constexpr int NCHUNK = 256;     // edge chunks per range
constexpr int CHUNK  = (E + NCHUNK - 1) / NCHUNK;  // 6250

__device__ __forceinline__ float bf2f(__hip_bfloat16 b) { return __bfloat162float(b); }

// ---------------- init: slot cursors + pooled-max buffer ----------------

__global__ void k_init(int* __restrict__ cursor, float* __restrict__ gbuf) {
    int i = blockIdx.x * 256 + threadIdx.x;
    if (i < N) cursor[i] = i * SLOTS;
    if (i < G * 128) gbuf[i] = 0.0f;
}

// ---------------- bucket: XCD-range-confined scatter into padded slots ----------------
// blockIdx&7 selects a dest range; blockIdx>>3 an edge chunk. Edge-index streams are
// non-temporal so they do NOT evict the L2-resident slot window (round-4 counters:
// WRITE 78 MB from stream-pollution evictions; nt fixed it in round 5).
// NOTE: nt is ONLY safe here (streamed once per range-set); nt on the slot reads in
// the gathers caused 102 MB of HBM refetch (round-5 counters) — do not reintroduce.

__global__ void __launch_bounds__(256) k_bucket(
        const int* __restrict__ row, const int* __restrict__ col,
        int* __restrict__ cursor, int* __restrict__ slots) {
    int r = blockIdx.x & (NRANGE - 1);
    int c = blockIdx.x >> 3;
    int lo = r * RSPAN, hi = lo + RSPAN;
    int e1 = min((c + 1) * CHUNK, E);
    for (int e = c * CHUNK + threadIdx.x; e < e1; e += 256) {
        int d = __builtin_nontemporal_load(col + e);
        if (d >= lo && d < hi) {
            int p = atomicAdd(&cursor[d], 1);
            int src = __builtin_nontemporal_load(row + e);
            if (p < d * SLOTS + SLOTS) slots[p] = src;
        }
    }
}

// dis = rsqrt(deg), deg = in-degree + 1 (self-loop); in-degree = cursor[n] - 48n
__global__ void k_dis(const int* __restrict__ cursor, float* __restrict__ dis) {
    int i = blockIdx.x * 256 + threadIdx.x;
    if (i < N) dis[i] = rsqrtf((float)(cursor[i] - i * SLOTS + 1));
}

// ---------------- layer 1: gather raw x (4 feats), thread per node ----------------

__global__ void __launch_bounds__(256) k_gather_x(
        const int* __restrict__ cursor, const int* __restrict__ slots,
        const float* __restrict__ dis, const float4* __restrict__ x,
        float4* __restrict__ aggx) {
    int n = blockIdx.x * 256 + threadIdx.x;
    if (n >= N) return;
    int s = n * SLOTS;
    int cnt = min(cursor[n] - s, SLOTS);
    float dn = dis[n];
    // accumulate sum_j dis[src_j] * x[src_j]; scale by dn at the end
    float4 a = make_float4(0.f, 0.f, 0.f, 0.f);
    int j = 0;
    for (; j + 4 <= cnt; j += 4) {
        int s0 = slots[s + j], s1 = slots[s + j + 1],
            s2 = slots[s + j + 2], s3 = slots[s + j + 3];
        float w0 = dis[s0], w1 = dis[s1], w2 = dis[s2], w3 = dis[s3];
        float4 v0 = x[s0], v1 = x[s1], v2 = x[s2], v3 = x[s3];
        a.x = fmaf(v0.x, w0, a.x); a.y = fmaf(v0.y, w0, a.y);
        a.z = fmaf(v0.z, w0, a.z); a.w = fmaf(v0.w, w0, a.w);
        a.x = fmaf(v1.x, w1, a.x); a.y = fmaf(v1.y, w1, a.y);
        a.z = fmaf(v1.z, w1, a.z); a.w = fmaf(v1.w, w1, a.w);
        a.x = fmaf(v2.x, w2, a.x); a.y = fmaf(v2.y, w2, a.y);
        a.z = fmaf(v2.z, w2, a.z); a.w = fmaf(v2.w, w2, a.w);
        a.x = fmaf(v3.x, w3, a.x); a.y = fmaf(v3.y, w3, a.y);
        a.z = fmaf(v3.z, w3, a.z); a.w = fmaf(v3.w, w3, a.w);
    }
    for (; j < cnt; j++) {
        int sx = slots[s + j];
        float w = dis[sx];
        float4 v = x[sx];
        a.x = fmaf(v.x, w, a.x); a.y = fmaf(v.y, w, a.y);
        a.z = fmaf(v.z, w, a.z); a.w = fmaf(v.w, w, a.w);
    }
    float4 xs = x[n];
    float sl = dn * dn;            // self-loop weight 1/deg
    a.x = fmaf(xs.x, sl, a.x * dn);
    a.y = fmaf(xs.y, sl, a.y * dn);
    a.z = fmaf(xs.z, sl, a.z * dn);
    a.w = fmaf(xs.w, sl, a.w * dn);
    aggx[n] = a;
}

// h = relu(aggx @ W1 + b1), stored bf16
__global__ void __launch_bounds__(256) k_layer1(
        const float4* __restrict__ aggx,
        const float* __restrict__ W1, const float* __restrict__ b1,
        __hip_bfloat16* __restrict__ h) {
    __shared__ float w1s[256];
    __shared__ float b1s[64];
    int tid = threadIdx.x;
    w1s[tid] = W1[tid];
    if (tid < 64) b1s[tid] = b1[tid];
    __syncthreads();
    int idx = blockIdx.x * 256 + tid;   // n*64 + f
    int n = idx >> 6;
    int f = idx & 63;
    if (n >= N) return;
    float4 a = aggx[n];
    float v = b1s[f];
    v = fmaf(a.x, w1s[f], v);
    v = fmaf(a.y, w1s[64 + f], v);
    v = fmaf(a.z, w1s[128 + f], v);
    v = fmaf(a.w, w1s[192 + f], v);
    h[idx] = __float2bfloat16(fmaxf(v, 0.0f));
}

// ---------------- layer 2 gather: one wave per node, lane = feature ----------------
// Edge list loaded lane-parallel once per node (coalesced), then broadcast via
// __shfl in the j-loop: inner loop = 2 shuffles + 1 h-row load + 1 FMA per edge,
// 8-wide unrolled for outstanding-load depth (L3-latency-bound).

__global__ void __launch_bounds__(256) k_gather_h(
        const int* __restrict__ cursor, const int* __restrict__ slots,
        const float* __restrict__ dis, const __hip_bfloat16* __restrict__ h,
        __hip_bfloat16* __restrict__ aggh) {
    int tid = threadIdx.x;
    int n = blockIdx.x * 4 + (tid >> 6);
    int lane = tid & 63;
    if (n >= N) return;
    int s = n * SLOTS;
    int cnt = min(cursor[n] - s, SLOTS);
    // lane-parallel prefetch of this node's edge list (cnt <= 48 < 64)
    int   psrc = 0;
    float pw   = 0.0f;
    if (lane < cnt) {
        psrc = slots[s + lane];
        pw   = dis[psrc];
    }
    float dn = dis[n];
    float acc = 0.0f;                  // sum_j dis[src_j] * h[src_j]; scale by dn later
    int j = 0;
    for (; j + 8 <= cnt; j += 8) {
        int   sr[8];
        float w[8], v[8];
        #pragma unroll
        for (int k = 0; k < 8; k++) sr[k] = __shfl(psrc, j + k);
        #pragma unroll
        for (int k = 0; k < 8; k++) w[k] = __shfl(pw, j + k);
        #pragma unroll
        for (int k = 0; k < 8; k++) v[k] = bf2f(h[(size_t)sr[k] * 64 + lane]);
        #pragma unroll
        for (int k = 0; k < 8; k++) acc = fmaf(w[k], v[k], acc);
    }
    for (; j < cnt; j++) {
        int   sx = __shfl(psrc, j);
        float wx = __shfl(pw, j);
        acc = fmaf(wx, bf2f(h[(size_t)sx * 64 + lane]), acc);
    }
    float self = bf2f(h[(size_t)n * 64 + lane]);
    aggh[(size_t)n * 64 + lane] =
        __float2bfloat16(fmaf(dn, self, acc) * dn);  // dn^2*self + dn*sum
}

// ---------------- fused: h2 = relu(aggh@W2+b2) -> segment_max into g ----------------
// Register-blocked: 4 nodes per wave, 16 per block.
// relu output >= 0, g init = 0  =>  int-bitwise atomicMax == float max.

__global__ void __launch_bounds__(256) k_layer2_pool(
        const __hip_bfloat16* __restrict__ aggh, const float* __restrict__ W2,
        const float* __restrict__ b2, float* __restrict__ g) {
    __shared__ float w2s[64 * 128];
    __shared__ float b2s[128];
    __shared__ float rows[16 * 64];
    int tid = threadIdx.x;
    for (int i = tid; i < 64 * 128; i += 256) w2s[i] = W2[i];
    if (tid < 128) b2s[tid] = b2[tid];
    int wid = tid >> 6, lane = tid & 63;
    __syncthreads();
    for (int base = blockIdx.x * 16; base < N; base += gridDim.x * 16) {
        int nrows = min(16, N - base);
        for (int i = tid; i < nrows * 64; i += 256)
            rows[i] = bf2f(aggh[(size_t)base * 64 + i]);
        __syncthreads();
        float acc[4][2];
        #pragma unroll
        for (int i = 0; i < 4; i++) { acc[i][0] = b2s[lane]; acc[i][1] = b2s[64 + lane]; }
        #pragma unroll 4
        for (int k = 0; k < 64; k++) {
            float w0 = w2s[k * 128 + lane];
            float w1 = w2s[k * 128 + 64 + lane];
            #pragma unroll
            for (int i = 0; i < 4; i++) {
                float r = rows[(wid * 4 + i) * 64 + k];       // LDS broadcast
                acc[i][0] = fmaf(r, w0, acc[i][0]);
                acc[i][1] = fmaf(r, w1, acc[i][1]);
            }
        }
        #pragma unroll
        for (int i = 0; i < 4; i++) {
            int n = base + wid * 4 + i;
            if (n < N) {
                float a0 = fmaxf(acc[i][0], 0.0f);
                float a1 = fmaxf(acc[i][1], 0.0f);
                int gr = n / NPG; if (gr > G - 1) gr = G - 1;
                atomicMax((int*)&g[gr * 128 + lane], __float_as_int(a0));
                atomicMax((int*)&g[gr * 128 + 64 + lane], __float_as_int(a1));
            }
        }
        __syncthreads();   // protect rows before next-iter overwrite
    }
}

// ---------------- conv1d branch: per-graph, LDS-staged, sliding window ----------------

__global__ void __launch_bounds__(256) k_conv(
        const float* __restrict__ target, const float* __restrict__ Wc,
        const float* __restrict__ bc, float* __restrict__ tb) {
    __shared__ float tg[L * 5];     // 20 KB: target[g] as [pos][ci]
    __shared__ float pm[4 * 64];
    int tid = threadIdx.x;
    int gi = blockIdx.x;
    const float* tsrc = target + (size_t)gi * (L * 5);
    for (int i = tid; i < L * 5; i += 256) tg[i] = tsrc[i];
    __syncthreads();
    int co = tid & 63, rr = tid >> 6;
    float wc[15];
    #pragma unroll
    for (int j = 0; j < 15; j++) wc[j] = Wc[co * 15 + j];
    int p0 = rr * 250;
    int pend = min(p0 + 250, 998);
    float a0 = tg[p0 * 5 + 0], a1 = tg[p0 * 5 + 1], a2 = tg[p0 * 5 + 2],
          a3 = tg[p0 * 5 + 3], a4 = tg[p0 * 5 + 4];
    float b0 = tg[p0 * 5 + 5], b1 = tg[p0 * 5 + 6], b2 = tg[p0 * 5 + 7],
          b3 = tg[p0 * 5 + 8], b4 = tg[p0 * 5 + 9];
    float m = -1e30f;
    for (int p = p0; p < pend; p++) {
        const float* cp = &tg[(p + 2) * 5];
        float c0 = cp[0], c1 = cp[1], c2 = cp[2], c3 = cp[3], c4 = cp[4];
        float v = 0.0f;
        v = fmaf(a0, wc[0],  v); v = fmaf(b0, wc[1],  v); v = fmaf(c0, wc[2],  v);
        v = fmaf(a1, wc[3],  v); v = fmaf(b1, wc[4],  v); v = fmaf(c1, wc[5],  v);
        v = fmaf(a2, wc[6],  v); v = fmaf(b2, wc[7],  v); v = fmaf(c2, wc[8],  v);
        v = fmaf(a3, wc[9],  v); v = fmaf(b3, wc[10], v); v = fmaf(c3, wc[11], v);
        v = fmaf(a4, wc[12], v); v = fmaf(b4, wc[13], v); v = fmaf(c4, wc[14], v);
        m = fmaxf(m, v);
        a0 = b0; a1 = b1; a2 = b2; a3 = b3; a4 = b4;
        b0 = c0; b1 = c1; b2 = c2; b3 = c3; b4 = c4;
    }
    pm[rr * 64 + co] = m;
    __syncthreads();
    if (tid < 64) {
        float mm = fmaxf(fmaxf(pm[tid], pm[64 + tid]), fmaxf(pm[128 + tid], pm[192 + tid]));
        tb[gi * 64 + tid] = fmaxf(mm + bc[tid], 0.0f);   // relu(max+bc) == max relu(v+bc)
    }
}

// ---------------- head ----------------

__global__ void __launch_bounds__(64) k_head(
        const float* __restrict__ g, const float* __restrict__ tb,
        const float* __restrict__ Wg, const float* __restrict__ bg,
        const float* __restrict__ Wt, const float* __restrict__ bt,
        const float* __restrict__ Wf, const float* __restrict__ bf,
        const float* __restrict__ Wo, const float* __restrict__ bo,
        float* __restrict__ out) {
    __shared__ float grs[128], ts[64], g2s[64], t2s[64], xcs[64];
    int tid = threadIdx.x;
    int gi = blockIdx.x;
    grs[tid]      = g[gi * 128 + tid];
    grs[64 + tid] = g[gi * 128 + 64 + tid];
    ts[tid]       = tb[gi * 64 + tid];
    __syncthreads();
    float a = bg[tid];
    #pragma unroll 8
    for (int k = 0; k < 128; k++) a = fmaf(grs[k], Wg[k * 64 + tid], a);
    float b = bt[tid];
    #pragma unroll 8
    for (int k = 0; k < 64; k++) b = fmaf(ts[k], Wt[k * 64 + tid], b);
    g2s[tid] = a;
    t2s[tid] = b;
    __syncthreads();
    float c = bf[tid];
    #pragma unroll 8
    for (int k = 0; k < 64; k++) c = fmaf(g2s[k], Wf[k * 64 + tid], c);
    #pragma unroll 8
    for (int k = 0; k < 64; k++) c = fmaf(t2s[k], Wf[(64 + k) * 64 + tid], c);
    c = fmaxf(c, 0.0f);
    xcs[tid] = c;
    __syncthreads();
    if (tid < 2) {
        float o = bo[tid];
        for (int k = 0; k < 64; k++) o = fmaf(xcs[k], Wo[k * 2 + tid], o);
        out[gi * 2 + tid] = o;
    }
}

// ---------------- launch ----------------

extern "C" void kernel_launch(void* const* d_in, const int* in_sizes, int n_in,
                              void* d_out, int out_size, void* d_ws, size_t ws_size,
                              hipStream_t stream) {
    const float* x      = (const float*)d_in[0];
    const int*   ei     = (const int*)d_in[1];   // [2, E] int32
    const float* target = (const float*)d_in[3];
    const float* W1 = (const float*)d_in[4];
    const float* b1 = (const float*)d_in[5];
    const float* W2 = (const float*)d_in[6];
    const float* b2 = (const float*)d_in[7];
    const float* Wg = (const float*)d_in[8];
    const float* bg = (const float*)d_in[9];
    const float* Wc = (const float*)d_in[10];
    const float* bc = (const float*)d_in[11];
    const float* Wt = (const float*)d_in[12];
    const float* bt = (const float*)d_in[13];
    const float* Wf = (const float*)d_in[14];
    const float* bf = (const float*)d_in[15];
    const float* Wo = (const float*)d_in[16];
    const float* bo = (const float*)d_in[17];
    float* out = (float*)d_out;

    const int* row = ei;
    const int* col = ei + E;

    // Workspace carve-up, 256B-aligned blocks
    char* base = (char*)d_ws;
    size_t o = 0;
    auto alloc = [&](size_t bytes) -> void* {
        void* p = base + o;
        o = (o + bytes + 255) & ~(size_t)255;
        return p;
    };
    int*      cursor = (int*)     alloc((size_t)N * 4);
    float*    dis    = (float*)   alloc((size_t)N * 4);
    int*      slots  = (int*)     alloc((size_t)N * SLOTS * 4);  // 19.2 MB
    float*    aggx   = (float*)   alloc((size_t)N * 4 * 4);
    __hip_bfloat16* h    = (__hip_bfloat16*)alloc((size_t)N * 64 * 2);
    __hip_bfloat16* aggh = (__hip_bfloat16*)alloc((size_t)N * 64 * 2);
    float*    gbuf   = (float*)   alloc((size_t)G * 128 * 4);
    float*    tb     = (float*)   alloc((size_t)G * 64 * 4);

    k_init       <<<(N + 255) / 256, 256, 0, stream>>>(cursor, gbuf);
    k_bucket     <<<NRANGE * NCHUNK, 256, 0, stream>>>(row, col, cursor, slots);
    k_dis        <<<(N + 255) / 256, 256, 0, stream>>>(cursor, dis);
    k_gather_x   <<<(N + 255) / 256, 256, 0, stream>>>(cursor, slots, dis,
                                                       (const float4*)x, (float4*)aggx);
    k_layer1     <<<(N * 64 + 255) / 256, 256, 0, stream>>>((const float4*)aggx, W1, b1, h);
    k_gather_h   <<<(N + 3) / 4, 256, 0, stream>>>(cursor, slots, dis, h, aggh);
    k_layer2_pool<<<1024, 256, 0, stream>>>(aggh, W2, b2, gbuf);
    k_conv       <<<G, 256, 0, stream>>>(target, Wc, bc, tb);
    k_head       <<<G, 64, 0, stream>>>(gbuf, tb, Wg, bg, Wt, bt, Wf, bf, Wo, bo, out);
}

// Round 7
// 363.861 us; speedup vs baseline: 1.1140x; 1.0002x over previous
//
#include <hip/hip_runtime.h>
#include <hip/hip_bf16.h>

// Problem constants (from reference)
constexpr int N   = 100000;   // nodes
constexpr int E   = 1600000;  // edges
constexpr int G   = 512;      // graphs
constexpr int L   = 1000;     // target seq len
constexpr int NPG = 195;      // N // G  (contiguous batch assignment)

// Padded-slot CSR: 48 slots per node. In-degree ~ Poisson(16); P(deg>48) ~ 3e-12
// per node => no real edge dropped; drop branches only guarantee memory safety.
constexpr int SLOTS  = 48;
constexpr int NRANGE = 8;       // dest ranges, XCD-pinned via blockIdx&7
constexpr int RSPAN  = 12500;   // nodes per range (2.4 MB slot window -> L2-resident)
constexpr int PCAP   = 208000;  // per-range partition capacity (mean 200k, +19 sigma)
constexpr int BCH    = 4096;    // edges per partition block
constexpr int PB     = 128;     // pass-B blocks per range

__device__ __forceinline__ float bf2f(__hip_bfloat16 b) { return __bfloat162float(b); }
__device__ __forceinline__ float lo_bf(unsigned v) { return __uint_as_float(v << 16); }
__device__ __forceinline__ float hi_bf(unsigned v) { return __uint_as_float(v & 0xFFFF0000u); }
__device__ __forceinline__ unsigned packbf2(float a, float b) {
    __hip_bfloat16 ha = __float2bfloat16(a), hb = __float2bfloat16(b);
    unsigned short ua = *(unsigned short*)&ha, ub = *(unsigned short*)&hb;
    return (unsigned)ua | ((unsigned)ub << 16);
}

// ---------------- init: slot cursors + partition counters ----------------

__global__ void k_init(int* __restrict__ cursor, int* __restrict__ pcnt) {
    int i = blockIdx.x * 256 + threadIdx.x;
    if (i < N) cursor[i] = i * SLOTS;
    if (i < 8 * 16) pcnt[i] = 0;
}

// ---------------- pass A: radix-partition edges by dest range ----------------
// Reads col/row ONCE (nt). Each block stages 4096 recs in LDS, reserves dense
// per-range output space with 8 global atomics, writes recs densely into its
// range partition. rec = (src << 14) | (dst - range_lo)   [17 + 14 = 31 bits]

__global__ void __launch_bounds__(256) k_part(
        const int* __restrict__ row, const int* __restrict__ col,
        int* __restrict__ pcnt, unsigned* __restrict__ precs) {
    __shared__ unsigned rec_s[BCH];
    __shared__ unsigned char rr_s[BCH];
    __shared__ int cnt_s[8], base_s[8], cur_s[8];
    int tid = threadIdx.x;
    if (tid < 8) cnt_s[tid] = 0;
    __syncthreads();
    int e0 = blockIdx.x * BCH;
    int nE = min(BCH, E - e0);
    for (int i = tid; i < nE; i += 256) {
        int e = e0 + i;
        int c = __builtin_nontemporal_load(col + e);
        int r = __builtin_nontemporal_load(row + e);
        int rr = c / RSPAN;                          // 0..7, magic-mul
        rec_s[i] = ((unsigned)r << 14) | (unsigned)(c - rr * RSPAN);
        rr_s[i] = (unsigned char)rr;
        atomicAdd(&cnt_s[rr], 1);
    }
    __syncthreads();
    if (tid < 8) { base_s[tid] = atomicAdd(&pcnt[tid * 16], cnt_s[tid]); cur_s[tid] = 0; }
    __syncthreads();
    for (int i = tid; i < nE; i += 256) {
        int rr = rr_s[i];
        int p = base_s[rr] + atomicAdd(&cur_s[rr], 1);
        if (p < PCAP) precs[(size_t)rr * PCAP + p] = rec_s[i];
    }
}

// ---------------- pass B: per-range scatter into padded slots ----------------
// blockIdx&7 = range (XCD-pinned). Input stream (~800 KB/range) AND the 2.4 MB
// slot window are both L2-resident on that XCD — no stream pollution.

__global__ void __launch_bounds__(256) k_bucket2(
        const int* __restrict__ pcnt, const unsigned* __restrict__ precs,
        int* __restrict__ cursor, int* __restrict__ slots) {
    int rr  = blockIdx.x & (NRANGE - 1);
    int sub = blockIdx.x >> 3;
    int cnt = min(pcnt[rr * 16], PCAP);
    int lo  = rr * RSPAN;
    const unsigned* pr = precs + (size_t)rr * PCAP;
    for (int i = sub * 256 + threadIdx.x; i < cnt; i += PB * 256) {
        unsigned rec = __builtin_nontemporal_load(pr + i);
        int d = lo + (int)(rec & 0x3FFFu);
        int p = atomicAdd(&cursor[d], 1);
        if (p < d * SLOTS + SLOTS) slots[p] = (int)(rec >> 14);
    }
}

// dis = rsqrt(deg), deg = in-degree + 1 (self-loop); in-degree = cursor[n] - 48n
__global__ void k_dis(const int* __restrict__ cursor, float* __restrict__ dis) {
    int i = blockIdx.x * 256 + threadIdx.x;
    if (i < N) dis[i] = rsqrtf((float)(cursor[i] - i * SLOTS + 1));
}

// ---------------- layer 1: gather raw x (4 feats), thread per node ----------------

__global__ void __launch_bounds__(256) k_gather_x(
        const int* __restrict__ cursor, const int* __restrict__ slots,
        const float* __restrict__ dis, const float4* __restrict__ x,
        float4* __restrict__ aggx) {
    int n = blockIdx.x * 256 + threadIdx.x;
    if (n >= N) return;
    int s = n * SLOTS;
    int cnt = min(cursor[n] - s, SLOTS);
    float dn = dis[n];
    float4 a = make_float4(0.f, 0.f, 0.f, 0.f);
    int j = 0;
    for (; j + 4 <= cnt; j += 4) {
        int s0 = slots[s + j], s1 = slots[s + j + 1],
            s2 = slots[s + j + 2], s3 = slots[s + j + 3];
        float w0 = dis[s0], w1 = dis[s1], w2 = dis[s2], w3 = dis[s3];
        float4 v0 = x[s0], v1 = x[s1], v2 = x[s2], v3 = x[s3];
        a.x = fmaf(v0.x, w0, a.x); a.y = fmaf(v0.y, w0, a.y);
        a.z = fmaf(v0.z, w0, a.z); a.w = fmaf(v0.w, w0, a.w);
        a.x = fmaf(v1.x, w1, a.x); a.y = fmaf(v1.y, w1, a.y);
        a.z = fmaf(v1.z, w1, a.z); a.w = fmaf(v1.w, w1, a.w);
        a.x = fmaf(v2.x, w2, a.x); a.y = fmaf(v2.y, w2, a.y);
        a.z = fmaf(v2.z, w2, a.z); a.w = fmaf(v2.w, w2, a.w);
        a.x = fmaf(v3.x, w3, a.x); a.y = fmaf(v3.y, w3, a.y);
        a.z = fmaf(v3.z, w3, a.z); a.w = fmaf(v3.w, w3, a.w);
    }
    for (; j < cnt; j++) {
        int sx = slots[s + j];
        float w = dis[sx];
        float4 v = x[sx];
        a.x = fmaf(v.x, w, a.x); a.y = fmaf(v.y, w, a.y);
        a.z = fmaf(v.z, w, a.z); a.w = fmaf(v.w, w, a.w);
    }
    float4 xs = x[n];
    float sl = dn * dn;            // self-loop weight 1/deg
    a.x = fmaf(xs.x, sl, a.x * dn);
    a.y = fmaf(xs.y, sl, a.y * dn);
    a.z = fmaf(xs.z, sl, a.z * dn);
    a.w = fmaf(xs.w, sl, a.w * dn);
    aggx[n] = a;
}

// h = relu(aggx @ W1 + b1), stored bf16
__global__ void __launch_bounds__(256) k_layer1(
        const float4* __restrict__ aggx,
        const float* __restrict__ W1, const float* __restrict__ b1,
        __hip_bfloat16* __restrict__ h) {
    __shared__ float w1s[256];
    __shared__ float b1s[64];
    int tid = threadIdx.x;
    w1s[tid] = W1[tid];
    if (tid < 64) b1s[tid] = b1[tid];
    __syncthreads();
    int idx = blockIdx.x * 256 + tid;   // n*64 + f
    int n = idx >> 6;
    int f = idx & 63;
    if (n >= N) return;
    float4 a = aggx[n];
    float v = b1s[f];
    v = fmaf(a.x, w1s[f], v);
    v = fmaf(a.y, w1s[64 + f], v);
    v = fmaf(a.z, w1s[128 + f], v);
    v = fmaf(a.w, w1s[192 + f], v);
    h[idx] = __float2bfloat16(fmaxf(v, 0.0f));
}

// ---------------- layer 2 gather: 2 nodes per wave, lane = 2 packed features --------
// h viewed as uint (bf16x2): lane li of each 32-lane half reads features {2li,2li+1}
// of its half's node -> each load instruction fetches 2 independent 128 B rows
// (double MLP, half the instructions). Edge lists staged in LDS per 8-node block.

__global__ void __launch_bounds__(256) k_gather_h(
        const int* __restrict__ cursor, const int* __restrict__ slots,
        const float* __restrict__ dis, const unsigned* __restrict__ h32,
        unsigned* __restrict__ aggh32) {
    __shared__ int   ls[8][SLOTS];
    __shared__ float lw[8][SLOTS];
    __shared__ int   lcnt[8];
    int tid = threadIdx.x;
    int nb = blockIdx.x * 8;
    if (tid < 8) {
        int node = nb + tid;
        lcnt[tid] = (node < N) ? min(cursor[node] - node * SLOTS, SLOTS) : 0;
    }
    __syncthreads();
    for (int i = tid; i < 8 * SLOTS; i += 256) {
        int lo = i / SLOTS, j = i % SLOTS;
        if (j < lcnt[lo]) {
            int src = slots[(nb + lo) * SLOTS + j];
            ls[lo][j] = src;
            lw[lo][j] = dis[src];
        }
    }
    __syncthreads();
    int wid = tid >> 6, lane = tid & 63;
    int half = lane >> 5, li = lane & 31;
    int local = wid * 2 + half;
    int n = nb + local;
    if (n >= N) return;
    int cnt = lcnt[local];
    float dn = dis[n];
    float acc0 = 0.0f, acc1 = 0.0f;
    int j = 0;
    for (; j + 8 <= cnt; j += 8) {
        unsigned v[8]; float w[8];
        #pragma unroll
        for (int k = 0; k < 8; k++) {
            int src = ls[local][j + k];
            v[k] = h32[(size_t)src * 32 + li];
            w[k] = lw[local][j + k];
        }
        #pragma unroll
        for (int k = 0; k < 8; k++) {
            acc0 = fmaf(w[k], lo_bf(v[k]), acc0);
            acc1 = fmaf(w[k], hi_bf(v[k]), acc1);
        }
    }
    for (; j < cnt; j++) {
        int src = ls[local][j];
        unsigned v = h32[(size_t)src * 32 + li];
        float w = lw[local][j];
        acc0 = fmaf(w, lo_bf(v), acc0);
        acc1 = fmaf(w, hi_bf(v), acc1);
    }
    unsigned sv = h32[(size_t)n * 32 + li];
    acc0 = fmaf(dn, lo_bf(sv), acc0) * dn;   // dn^2*self + dn*sum
    acc1 = fmaf(dn, hi_bf(sv), acc1) * dn;
    aggh32[(size_t)n * 32 + li] = packbf2(acc0, acc1);
}

// ---------------- fused: relu(aggh@W2+b2) -> per-graph max -> full head ----------------
// One block per graph: pooled max kept in registers/LDS (zero global atomics),
// then the whole head (Wg, Wt, Wf, Wo) computed by wave 0. relu >= 0 => max-init 0.

__global__ void __launch_bounds__(256) k_pool_head(
        const __hip_bfloat16* __restrict__ aggh, const float* __restrict__ W2,
        const float* __restrict__ b2, const float* __restrict__ tb,
        const float* __restrict__ Wg, const float* __restrict__ bg,
        const float* __restrict__ Wt, const float* __restrict__ bt,
        const float* __restrict__ Wf, const float* __restrict__ bf,
        const float* __restrict__ Wo, const float* __restrict__ bo,
        float* __restrict__ out) {
    __shared__ float w2s[64 * 128];
    __shared__ float b2s[128];
    __shared__ float rows[16 * 64];
    __shared__ float red[4 * 128];
    __shared__ float gvec[128], ts[64], g2s[64], t2s[64], xcs[64];
    int tid = threadIdx.x;
    int gi = blockIdx.x;
    int n0 = gi * NPG;
    int n1 = (gi == G - 1) ? N : n0 + NPG;
    for (int i = tid; i < 64 * 128; i += 256) w2s[i] = W2[i];
    if (tid < 128) b2s[tid] = b2[tid];
    int wid = tid >> 6, lane = tid & 63;
    float gm0 = 0.0f, gm1 = 0.0f;
    __syncthreads();
    for (int base = n0; base < n1; base += 16) {
        int nrows = min(16, n1 - base);
        for (int i = tid; i < nrows * 64; i += 256)
            rows[i] = bf2f(aggh[(size_t)base * 64 + i]);
        __syncthreads();
        float acc[4][2];
        #pragma unroll
        for (int i = 0; i < 4; i++) { acc[i][0] = b2s[lane]; acc[i][1] = b2s[64 + lane]; }
        #pragma unroll 4
        for (int k = 0; k < 64; k++) {
            float w0 = w2s[k * 128 + lane];
            float w1 = w2s[k * 128 + 64 + lane];
            #pragma unroll
            for (int i = 0; i < 4; i++) {
                float r = rows[(wid * 4 + i) * 64 + k];       // LDS broadcast
                acc[i][0] = fmaf(r, w0, acc[i][0]);
                acc[i][1] = fmaf(r, w1, acc[i][1]);
            }
        }
        #pragma unroll
        for (int i = 0; i < 4; i++) {
            if (base + wid * 4 + i < n1) {
                gm0 = fmaxf(gm0, fmaxf(acc[i][0], 0.0f));
                gm1 = fmaxf(gm1, fmaxf(acc[i][1], 0.0f));
            }
        }
        __syncthreads();
    }
    red[wid * 128 + lane]      = gm0;
    red[wid * 128 + 64 + lane] = gm1;
    __syncthreads();
    if (wid == 0) {
        float m0 = fmaxf(fmaxf(red[lane], red[128 + lane]),
                         fmaxf(red[256 + lane], red[384 + lane]));
        float m1 = fmaxf(fmaxf(red[64 + lane], red[192 + lane]),
                         fmaxf(red[320 + lane], red[448 + lane]));
        gvec[lane]      = m0;
        gvec[64 + lane] = m1;
        ts[lane] = tb[gi * 64 + lane];
        // head (single wave; LDS RAW within wave is lockstep-safe)
        float a = bg[lane];
        #pragma unroll 8
        for (int k = 0; k < 128; k++) a = fmaf(gvec[k], Wg[k * 64 + lane], a);
        float b = bt[lane];
        #pragma unroll 8
        for (int k = 0; k < 64; k++) b = fmaf(ts[k], Wt[k * 64 + lane], b);
        g2s[lane] = a;
        t2s[lane] = b;
        float c = bf[lane];
        #pragma unroll 8
        for (int k = 0; k < 64; k++) c = fmaf(g2s[k], Wf[k * 64 + lane], c);
        #pragma unroll 8
        for (int k = 0; k < 64; k++) c = fmaf(t2s[k], Wf[(64 + k) * 64 + lane], c);
        xcs[lane] = fmaxf(c, 0.0f);
        if (lane < 2) {
            float o = bo[lane];
            for (int k = 0; k < 64; k++) o = fmaf(xcs[k], Wo[k * 2 + lane], o);
            out[gi * 2 + lane] = o;
        }
    }
}

// ---------------- conv1d branch: per-graph, LDS-staged, sliding window ----------------

__global__ void __launch_bounds__(256) k_conv(
        const float* __restrict__ target, const float* __restrict__ Wc,
        const float* __restrict__ bc, float* __restrict__ tb) {
    __shared__ float tg[L * 5];     // 20 KB: target[g] as [pos][ci]
    __shared__ float pm[4 * 64];
    int tid = threadIdx.x;
    int gi = blockIdx.x;
    const float* tsrc = target + (size_t)gi * (L * 5);
    for (int i = tid; i < L * 5; i += 256) tg[i] = tsrc[i];
    __syncthreads();
    int co = tid & 63, rr = tid >> 6;
    float wc[15];
    #pragma unroll
    for (int j = 0; j < 15; j++) wc[j] = Wc[co * 15 + j];
    int p0 = rr * 250;
    int pend = min(p0 + 250, 998);
    float a0 = tg[p0 * 5 + 0], a1 = tg[p0 * 5 + 1], a2 = tg[p0 * 5 + 2],
          a3 = tg[p0 * 5 + 3], a4 = tg[p0 * 5 + 4];
    float b0 = tg[p0 * 5 + 5], b1 = tg[p0 * 5 + 6], b2 = tg[p0 * 5 + 7],
          b3 = tg[p0 * 5 + 8], b4 = tg[p0 * 5 + 9];
    float m = -1e30f;
    for (int p = p0; p < pend; p++) {
        const float* cp = &tg[(p + 2) * 5];
        float c0 = cp[0], c1 = cp[1], c2 = cp[2], c3 = cp[3], c4 = cp[4];
        float v = 0.0f;
        v = fmaf(a0, wc[0],  v); v = fmaf(b0, wc[1],  v); v = fmaf(c0, wc[2],  v);
        v = fmaf(a1, wc[3],  v); v = fmaf(b1, wc[4],  v); v = fmaf(c1, wc[5],  v);
        v = fmaf(a2, wc[6],  v); v = fmaf(b2, wc[7],  v); v = fmaf(c2, wc[8],  v);
        v = fmaf(a3, wc[9],  v); v = fmaf(b3, wc[10], v); v = fmaf(c3, wc[11], v);
        v = fmaf(a4, wc[12], v); v = fmaf(b4, wc[13], v); v = fmaf(c4, wc[14], v);
        m = fmaxf(m, v);
        a0 = b0; a1 = b1; a2 = b2; a3 = b3; a4 = b4;
        b0 = c0; b1 = c1; b2 = c2; b3 = c3; b4 = c4;
    }
    pm[rr * 64 + co] = m;
    __syncthreads();
    if (tid < 64) {
        float mm = fmaxf(fmaxf(pm[tid], pm[64 + tid]), fmaxf(pm[128 + tid], pm[192 + tid]));
        tb[gi * 64 + tid] = fmaxf(mm + bc[tid], 0.0f);   // relu(max+bc) == max relu(v+bc)
    }
}

// ---------------- launch ----------------

extern "C" void kernel_launch(void* const* d_in, const int* in_sizes, int n_in,
                              void* d_out, int out_size, void* d_ws, size_t ws_size,
                              hipStream_t stream) {
    const float* x      = (const float*)d_in[0];
    const int*   ei     = (const int*)d_in[1];   // [2, E] int32
    const float* target = (const float*)d_in[3];
    const float* W1 = (const float*)d_in[4];
    const float* b1 = (const float*)d_in[5];
    const float* W2 = (const float*)d_in[6];
    const float* b2 = (const float*)d_in[7];
    const float* Wg = (const float*)d_in[8];
    const float* bg = (const float*)d_in[9];
    const float* Wc = (const float*)d_in[10];
    const float* bc = (const float*)d_in[11];
    const float* Wt = (const float*)d_in[12];
    const float* bt = (const float*)d_in[13];
    const float* Wf = (const float*)d_in[14];
    const float* bf = (const float*)d_in[15];
    const float* Wo = (const float*)d_in[16];
    const float* bo = (const float*)d_in[17];
    float* out = (float*)d_out;

    const int* row = ei;
    const int* col = ei + E;

    // Workspace carve-up, 256B-aligned blocks (~54 MB)
    char* base = (char*)d_ws;
    size_t o = 0;
    auto alloc = [&](size_t bytes) -> void* {
        void* p = base + o;
        o = (o + bytes + 255) & ~(size_t)255;
        return p;
    };
    int*      cursor = (int*)     alloc((size_t)N * 4);
    float*    dis    = (float*)   alloc((size_t)N * 4);
    int*      slots  = (int*)     alloc((size_t)N * SLOTS * 4);        // 19.2 MB
    int*      pcnt   = (int*)     alloc(8 * 16 * 4);                   // 64B-strided
    unsigned* precs  = (unsigned*)alloc((size_t)NRANGE * PCAP * 4);    // 6.7 MB
    float*    aggx   = (float*)   alloc((size_t)N * 4 * 4);
    __hip_bfloat16* h    = (__hip_bfloat16*)alloc((size_t)N * 64 * 2);
    __hip_bfloat16* aggh = (__hip_bfloat16*)alloc((size_t)N * 64 * 2);
    float*    tb     = (float*)   alloc((size_t)G * 64 * 4);

    k_init     <<<(N + 255) / 256, 256, 0, stream>>>(cursor, pcnt);
    k_part     <<<(E + BCH - 1) / BCH, 256, 0, stream>>>(row, col, pcnt, precs);
    k_bucket2  <<<NRANGE * PB, 256, 0, stream>>>(pcnt, precs, cursor, slots);
    k_dis      <<<(N + 255) / 256, 256, 0, stream>>>(cursor, dis);
    k_gather_x <<<(N + 255) / 256, 256, 0, stream>>>(cursor, slots, dis,
                                                     (const float4*)x, (float4*)aggx);
    k_layer1   <<<(N * 64 + 255) / 256, 256, 0, stream>>>((const float4*)aggx, W1, b1, h);
    k_gather_h <<<(N + 7) / 8, 256, 0, stream>>>(cursor, slots, dis,
                                                 (const unsigned*)h, (unsigned*)aggh);
    k_conv     <<<G, 256, 0, stream>>>(target, Wc, bc, tb);
    k_pool_head<<<G, 256, 0, stream>>>(aggh, W2, b2, tb, Wg, bg, Wt, bt,
                                       Wf, bf, Wo, bo, out);
}